// Round 4
// baseline (1426.287 us; speedup 1.0000x reference)
//
#include <hip/hip_runtime.h>
#include <math.h>

#define MU_F 0.1f
#define SHRINK_F 0.01f   // LMBD * MU
#define BN_EPS_F 1e-5f

typedef _Float16 half_t;
typedef _Float16 half8 __attribute__((ext_vector_type(8)));
typedef float f32x4 __attribute__((ext_vector_type(4)));

// async global->LDS, 16B per lane. LDS dest is wave-uniform base + lane*16.
__device__ __forceinline__ void gll16(const half_t* g, half_t* l) {
    __builtin_amdgcn_global_load_lds(
        (const __attribute__((address_space(1))) void*)g,
        (__attribute__((address_space(3))) void*)l, 16, 0, 0);
}

// counted-vmcnt wait + raw barrier, split per the verified 8-phase idiom
// (separate asm statements + sched_barrier(0) fence; rule #18 hygiene).
#define VM_WAIT_BARRIER(N) do {                                   \
    asm volatile("s_waitcnt vmcnt(" #N ")" ::: "memory");         \
    __builtin_amdgcn_s_barrier();                                 \
    __builtin_amdgcn_sched_barrier(0);                            \
} while (0)

// ---------------------------------------------------------------------------
// MFMA implicit-GEMM conv, m97-tile + T3/T4 deep async pipeline:
//   block = 128co x 128px (batch folded into px: NPX = 32*Hd*Wd = 25088,
//   exact 128-tiles -> 196 px-tiles, no dead blocks)
//   4 waves (2co x 2px) of 64x64 -> 16 MFMA : 4 DMA per wave per chunk (K=32)
//   staging via global_load_lds dwordx4 into FOUR LDS buffers (16KB each),
//   lookahead 3: chunk k+3 issued at iter k; steady-state s_waitcnt vmcnt(8)
//   (12 in flight, oldest chunk's 4 retired), tail ladder 8->4->0.
//   Ring R=4 >= lookahead+1: no WAR hazard.
//   OOB taps -> 256B zero page (DMA is unconditional per row).
//   LDS: 256 rows x 64B linear; 16B slot XOR-swizzle (slot = q ^ (row&3))
//   applied on global SOURCE and on ds_read (same involution, rule 21).
//   Bijective XCD swizzle (m204 form).
// MODE 2 work balance: quadrant in LOW 2 bits of bx (q = bx&3, tile = bx>>2)
//   so each XCD gets all four quadrant weights (8..32 chunks) evenly, and
//   adjacent blocks (same tile, 4 quadrants) share the same B window in L2.
//   [round-3 bug: q = bx/196 put 8-chunk blocks on XCD0-1, 32-chunk on 6-7]
// MODE 0: fwd conv stride S pad PAD; MODE 1: convT s1 (pad 1);
// MODE 2: convT s2 (pad 1, outpad 1) via parity-quadrant px mapping.
// Frag layout (16x16x32): A row=l&15, k=(l>>4)*8+j ; B col=l&15 same k;
// C/D col=l&15, row=(l>>4)*4+reg  [m89-verified].
// NOTE: auxH/outH are NOT __restrict__ — the first MODE2 call reads x (NHWC
// half) and writes the residual to the SAME buffer element-in-place (each
// element read then written by the same thread only).
// ---------------------------------------------------------------------------
template<int KS, int S, int PAD, int MODE>
__global__ __launch_bounds__(256, 2)
void conv_big(const half_t* __restrict__ Ag, const half_t* __restrict__ Xh,
              float* __restrict__ outF, half_t* outH,
              const half_t* auxH, const float* __restrict__ auxF,
              int CA, int Cout, int Hin, int Win, int Hout, int Wout, int ptiles,
              float alpha, float beta, float delta, int relu1,
              const float* __restrict__ pscale, const float* __restrict__ pbias,
              const float* __restrict__ aux3, int relu2,
              const half_t* __restrict__ zpg)
{
    __shared__ __align__(16) half_t sm[4 * 8192];   // 4 bufs x 256 rows x 32 halves = 64 KB

    const int tid = threadIdx.x;
    const int wv = tid >> 6, ln = tid & 63;
    const int co0 = blockIdx.y * 128;
    const int wco = (wv & 1) * 64, wpx = (wv >> 1) * 64;

    // bijective XCD swizzle (m204): works for any gridDim.x
    int bx;
    {
        const int nwg = gridDim.x;
        const int q = nwg >> 3, r8 = nwg & 7;
        const int xcd = blockIdx.x & 7, idx = blockIdx.x >> 3;
        bx = (xcd < r8 ? xcd * (q + 1) : r8 * (q + 1) + (xcd - r8) * q) + idx;
    }

    int eh = 0, ew = 0, p0;
    if (MODE == 2) {
        int qq = bx & 3;               // quadrant in LOW bits: XCD-balanced
        p0 = (bx >> 2) * 128;
        eh = qq >> 1; ew = qq & 1;
    } else {
        p0 = bx * 128;
    }
    (void)ptiles;

    const int Wd   = (MODE == 2) ? (Wout >> 1) : Wout;
    const int Hd   = (MODE == 2) ? (Hout >> 1) : Hout;
    const int PHW1 = Hd * Wd;
    const int NPX  = PHW1 * 32;          // batch 32 folded into px space
    const int K9   = KS * KS * CA;

    const int r  = tid >> 2;             // 0..63: row within a 64-row DMA pass
    const int s4 = tid & 3;              // 16B slot
    const int sw = (s4 ^ (r & 3)) << 3;  // swizzled half-offset within 32-half chunk

    const size_t abase0 = (size_t)(co0 + r     ) * K9;   // A pass 0: co rows 0..63
    const size_t abase1 = (size_t)(co0 + r + 64) * K9;   // A pass 1: co rows 64..127

    int bph[2], bpw[2]; bool bval[2]; size_t bnb[2];
#pragma unroll
    for (int i = 0; i < 2; ++i) {
        int px = p0 + i * 64 + r;
        bval[i] = px < NPX;
        int pc = bval[i] ? px : 0;
        int n2 = pc / PHW1; int rem = pc - n2 * PHW1;
        int ph = rem / Wd;
        bph[i] = ph; bpw[i] = rem - ph * Wd;
        bnb[i] = (size_t)n2 * Hin * Win;
    }

    const int cpt = CA >> 5;             // 32-ch chunks per tap (4 or 8)
    const int lgc = (cpt == 8) ? 3 : 2;
    int ntap, lgj = 0, phh = 0, pww = 0;
    if (MODE == 2) {
        phh = (eh + 1) & 1; pww = (ew + 1) & 1;
        lgj = ew;
        ntap = (1 + eh) * (1 + ew);
    } else {
        ntap = KS * KS;
    }
    const int total = ntap << lgc;       // >= 4 at every call site

    // issue one chunk's 4 DMA passes (2 x A 64-rows, 2 x B 64-rows) into dst
    auto issue = [&](int flat, half_t* dst) {
        const int ci = flat & (cpt - 1);
        const int ti = flat >> lgc;
        int kh, kw;
        if (MODE == 2) {
            int i2 = ti >> lgj, j = ti & ((1 << lgj) - 1);
            kh = phh + 2 * i2; kw = pww + 2 * j;
        } else if (KS == 3) {
            kh = (ti * 11) >> 5; kw = ti - 3 * kh;   // div-by-3, ti<9
        } else { kh = 0; kw = 0; }
        const int c0 = ci << 5;
        const size_t koff = (size_t)(kh * KS + kw) * CA + c0 + sw;
        gll16(Ag + abase0 + koff, dst +        tid * 8);
        gll16(Ag + abase1 + koff, dst + 2048 + tid * 8);
#pragma unroll
        for (int i = 0; i < 2; ++i) {
            int hh, ww2; bool ok = bval[i];
            if (MODE == 0) {
                hh = bph[i] * S - PAD + kh; ww2 = bpw[i] * S - PAD + kw;
                ok = ok && (unsigned)hh < (unsigned)Hin && (unsigned)ww2 < (unsigned)Win;
            } else if (MODE == 1) {
                hh = bph[i] + PAD - kh; ww2 = bpw[i] + PAD - kw;
                ok = ok && (unsigned)hh < (unsigned)Hin && (unsigned)ww2 < (unsigned)Win;
            } else {
                int nh = 2 * bph[i] + eh + PAD - kh, nw = 2 * bpw[i] + ew + PAD - kw;
                hh = nh >> 1; ww2 = nw >> 1;
                ok = ok && nh >= 0 && nw >= 0 && hh < Hin && ww2 < Win;
            }
            const half_t* src = ok
                ? Xh + (bnb[i] + (size_t)(hh * Win + ww2)) * CA + c0 + sw
                : zpg;
            gll16(src, dst + 4096 + i * 2048 + tid * 8);
        }
    };

    f32x4 acc[4][4] = {};

    // prologue: chunks 0,1,2 in flight (12 instr); wait oldest 4, barrier
    issue(0, sm);
    issue(1, sm + 8192);
    issue(2, sm + 16384);
    VM_WAIT_BARRIER(8);

    const int fr = ln & 15, q8 = ln >> 4;
    const int sx = (q8 ^ (fr & 3)) << 3;
    const int rdA = (wco + fr) * 32 + sx;
    const int rdB = (128 + wpx + fr) * 32 + sx;

    for (int k = 0; k < total; ++k) {
        half_t* bufr = sm + (k & 3) * 8192;
        if (k + 3 < total)
            issue(k + 3, sm + ((k + 3) & 3) * 8192);
        half8 fa[4], fb[4];
#pragma unroll
        for (int m = 0; m < 4; ++m)
            fa[m] = *(const half8*)(bufr + rdA + m * 512);
#pragma unroll
        for (int t2 = 0; t2 < 4; ++t2)
            fb[t2] = *(const half8*)(bufr + rdB + t2 * 512);
#pragma unroll
        for (int m = 0; m < 4; ++m)
#pragma unroll
            for (int t2 = 0; t2 < 4; ++t2)
                acc[m][t2] = __builtin_amdgcn_mfma_f32_16x16x32_f16(fa[m], fb[t2], acc[m][t2], 0, 0, 0);
        // block-uniform branch ladder (total, k uniform)
        if (k + 3 < total)      VM_WAIT_BARRIER(8);   // ensure chunk k+1 landed
        else if (k + 2 < total) VM_WAIT_BARRIER(4);
        else if (k + 1 < total) VM_WAIT_BARRIER(0);
    }

    // epilogue
    const int rg = ln >> 4;
#pragma unroll
    for (int t = 0; t < 4; ++t) {
        int px = p0 + wpx + t * 16 + fr;
        if (px >= NPX) continue;
        int n2 = px / PHW1; int rem = px - n2 * PHW1;
        int ph = rem / Wd, pw = rem - ph * Wd;
        int oh, ow;
        if (MODE == 2) { oh = 2 * ph + eh; ow = 2 * pw + ew; }
        else           { oh = ph;          ow = pw; }
        size_t ghwc = ((size_t)(n2 * Hout + oh) * Wout + ow) * Cout;
#pragma unroll
        for (int m = 0; m < 4; ++m) {
#pragma unroll
            for (int rr = 0; rr < 4; ++rr) {
                int co_l = co0 + wco + m * 16 + rg * 4 + rr;
                size_t fidx = ((size_t)(n2 * Cout + co_l) * Hout + oh) * Wout + ow;
                float v = alpha * acc[m][t][rr] + delta;
                if (auxH) v += beta * (float)auxH[ghwc + co_l];
                if (auxF) v += beta * auxF[fidx];
                if (relu1) v = fmaxf(v, 0.f);
                if (pscale) v = pscale[co_l] * v + pbias[co_l];
                if (aux3) v += aux3[fidx];
                if (relu2) v = fmaxf(v, 0.f);
                if (outH) outH[ghwc + co_l] = (half_t)v;
                else      outF[fidx] = v;
            }
        }
    }
}

template<int KT>
__global__ __launch_bounds__(256)
void pack_w(const float* __restrict__ W, half_t* __restrict__ Wh,
            half_t* __restrict__ WTh, int Cin, int Cout, int do_norm)
{
    __shared__ float red[256];
    int co = blockIdx.x, tid = threadIdx.x;
    int CK = Cin * KT;
    const float* w = W + (size_t)co * CK;
    float inv = 1.f;
    if (do_norm) {
        float s = 0.f;
        for (int i = tid; i < CK; i += 256) { float v = w[i]; s += v * v; }
        red[tid] = s; __syncthreads();
        for (int o = 128; o > 0; o >>= 1) {
            if (tid < o) red[tid] += red[tid + o];
            __syncthreads();
        }
        inv = 1.f / (sqrtf(red[0]) + 1e-12f);
    }
    for (int i = tid; i < CK; i += 256) {
        int ci = i / KT, tap = i - ci * KT;
        half_t h = (half_t)(w[i] * inv);
        Wh[((size_t)co * KT + tap) * Cin + ci] = h;
        if (WTh) WTh[((size_t)ci * KT + tap) * Cout + co] = h;
    }
}

__global__ __launch_bounds__(256)
void tx_kernel(const float* __restrict__ x, half_t* __restrict__ xTh)
{
    __shared__ __align__(16) half_t tl[56 * 136];
    int h = blockIdx.x, n = blockIdx.y, tid = threadIdx.x;
    for (int it = 0; it < 28; ++it) {
        int id = tid + it * 256;
        int c = id / 56, w0 = id - c * 56;
        tl[w0 * 136 + c] = (half_t)x[(((size_t)n * 128 + c) * 56 + h) * 56 + w0];
    }
    __syncthreads();
    if (tid < 224) {
        int w0 = tid >> 2, part = tid & 3;
        size_t base = (((size_t)n * 56 + h) * 56 + w0) * 128 + part * 32;
#pragma unroll
        for (int j = 0; j < 4; ++j)
            *(half8*)(xTh + base + j * 8) = *(const half8*)(tl + w0 * 136 + part * 32 + j * 8);
    }
}

__global__ __launch_bounds__(256)
void comb_kernel(const half_t* __restrict__ c, const half_t* __restrict__ p,
                 half_t* __restrict__ a, float w1, float w2, int n8)
{
    int i = blockIdx.x * 256 + threadIdx.x;
    if (i >= n8) return;
    half8 cv = ((const half8*)c)[i];
    half8 pv = ((const half8*)p)[i];
    half8 rres;
#pragma unroll
    for (int j = 0; j < 8; ++j) rres[j] = (half_t)(w1 * (float)cv[j] + w2 * (float)pv[j]);
    ((half8*)a)[i] = rres;
}

__global__ __launch_bounds__(256)
void bn_prep_kernel(const float* __restrict__ g, const float* __restrict__ b,
                    const float* __restrict__ m, const float* __restrict__ v,
                    float* __restrict__ s, float* __restrict__ t, int C)
{
    int i = blockIdx.x * 256 + threadIdx.x;
    if (i < C) {
        float sc = g[i] * rsqrtf(v[i] + BN_EPS_F);
        s[i] = sc; t[i] = b[i] - m[i] * sc;
    }
}

__global__ __launch_bounds__(128)
void zfill_kernel(half_t* __restrict__ p)
{
    p[threadIdx.x] = (half_t)0.f;   // 256 B zero page for OOB DMA redirect
}

extern "C" void kernel_launch(void* const* d_in, const int* in_sizes, int n_in,
                              void* d_out, int out_size, void* d_ws, size_t ws_size,
                              hipStream_t stream)
{
    (void)in_sizes; (void)n_in; (void)out_size;
    const float* x    = (const float*)d_in[0];
    const float* W1   = (const float*)d_in[1];
    const float* W2   = (const float*)d_in[2];
    const float* Wsc  = (const float*)d_in[3];
    const float* bn1g = (const float*)d_in[4];
    const float* bn1b = (const float*)d_in[5];
    const float* bn1m = (const float*)d_in[6];
    const float* bn1v = (const float*)d_in[7];
    const float* bn2g = (const float*)d_in[8];
    const float* bn2b = (const float*)d_in[9];
    const float* bn2m = (const float*)d_in[10];
    const float* bn2v = (const float*)d_in[11];
    const float* bscg = (const float*)d_in[12];
    const float* bscb = (const float*)d_in[13];
    const float* bscm = (const float*)d_in[14];
    const float* bscv = (const float*)d_in[15];

    const size_t NB = (size_t)32 * 256 * 28 * 28;
    const size_t NX = (size_t)32 * 128 * 56 * 56;

    char* base = (char*)d_ws;
    size_t off = 0;
    auto alloc = [&](size_t nbytes) -> void* {
        void* r = base + off;
        off = (off + nbytes + 255) & ~(size_t)255;
        return r;
    };
    half_t* Wh1  = (half_t*)alloc(294912 * 2);
    half_t* WTh1 = (half_t*)alloc(294912 * 2);
    half_t* Wh2  = (half_t*)alloc(589824 * 2);
    half_t* WTh2 = (half_t*)alloc(589824 * 2);
    half_t* Wsch = (half_t*)alloc(32768 * 2);
    float* bn1s = (float*)alloc(256 * 4);  float* bn1t = (float*)alloc(256 * 4);
    float* bn2s = (float*)alloc(256 * 4);  float* bn2t = (float*)alloc(256 * 4);
    float* bscs = (float*)alloc(256 * 4);  float* bsct = (float*)alloc(256 * 4);
    half_t* zpg  = (half_t*)alloc(256);
    half_t* xTh  = (half_t*)alloc(NX * 2);   // aliased as r56h after shortcut+c0 consume it
    half_t* r56h = xTh;
    half_t* Pa   = (half_t*)alloc(NB * 2);
    half_t* Pb   = (half_t*)alloc(NB * 2);
    half_t* Pc   = (half_t*)alloc(NB * 2);
    half_t* Py   = (half_t*)alloc(NB * 2);
    half_t* r28h = (half_t*)alloc(NB * 2);
    float*  scF  = (float*)alloc(NB * 4);
    if (off > ws_size) return;

    float* outp = (float*)d_out;

    double t = 1.0; float al[3];
    for (int i = 0; i < 3; ++i) {
        double tn = (1.0 + sqrt(1.0 + 4.0 * t * t)) / 2.0;
        al[i] = (float)((t - 1.0) / tn); t = tn;
    }

    const dim3 blk(256);
    const dim3 cblk(256);
    const dim3 gB(196, 2, 1);      // 25088 px / 128 exact, 2 co-tiles (Cout=256)
    const dim3 gT2(784, 1, 1);     // 196 px-tiles x 4 quadrants (low bits)
    const int n8 = (int)(NB / 8);
    const dim3 gC((n8 + 255) / 256);
    const float* NF = nullptr;
    const half_t* NH = nullptr;
    float* NFo = nullptr;
    half_t* NHo = nullptr;

    pack_w<9><<<256, blk, 0, stream>>>(W1, Wh1, WTh1, 128, 256, 1);
    pack_w<9><<<256, blk, 0, stream>>>(W2, Wh2, WTh2, 256, 256, 1);
    pack_w<1><<<256, blk, 0, stream>>>(Wsc, Wsch, nullptr, 128, 256, 0);
    bn_prep_kernel<<<1, blk, 0, stream>>>(bn1g, bn1b, bn1m, bn1v, bn1s, bn1t, 256);
    bn_prep_kernel<<<1, blk, 0, stream>>>(bn2g, bn2b, bn2m, bn2v, bn2s, bn2t, 256);
    bn_prep_kernel<<<1, blk, 0, stream>>>(bscg, bscb, bscm, bscv, bscs, bsct, 256);
    zfill_kernel<<<1, dim3(128), 0, stream>>>(zpg);
    tx_kernel<<<dim3(56, 32), blk, 0, stream>>>(x, xTh);

    // ================= Stage A: dict_conv(x, W1, stride 2) =================
    conv_big<3,2,1,0><<<gB, cblk, 0, stream>>>(Wh1, xTh, NFo, Pa, NH, NF,
        128, 256, 56, 56, 28, 28, 196, MU_F, 0.f, -SHRINK_F, 1, NF, NF, NF, 0, zpg);
    conv_big<1,2,0,0><<<gB, cblk, 0, stream>>>(Wsch, xTh, scF, NHo, NH, NF,
        128, 256, 56, 56, 28, 28, 196, 1.f, 0.f, 0.f, 0, bscs, bsct, NF, 0, zpg);

    // residual #1: read x as NHWC half from xTh, overwrite same buffer in place
    conv_big<3,2,1,2><<<gT2, cblk, 0, stream>>>(WTh1, Pa, NFo, r56h, xTh, NF,
        256, 128, 28, 28, 56, 56, 196, -1.f, 1.f, 0.f, 0, NF, NF, NF, 0, zpg);
    conv_big<3,2,1,0><<<gB, cblk, 0, stream>>>(Wh1, r56h, NFo, Pb, Pa, NF,
        128, 256, 56, 56, 28, 28, 196, MU_F, 1.f, -SHRINK_F, 1, NF, NF, NF, 0, zpg);

    comb_kernel<<<gC, blk, 0, stream>>>(Pb, Pa, Pc, 1.f + al[1], -al[1], n8);
    conv_big<3,2,1,2><<<gT2, cblk, 0, stream>>>(WTh1, Pc, NFo, r56h, NH, x,
        256, 128, 28, 28, 56, 56, 196, -1.f, 1.f, 0.f, 0, NF, NF, NF, 0, zpg);
    conv_big<3,2,1,0><<<gB, cblk, 0, stream>>>(Wh1, r56h, NFo, Pa, Pc, NF,
        128, 256, 56, 56, 28, 28, 196, MU_F, 1.f, -SHRINK_F, 1, NF, NF, NF, 0, zpg);

    comb_kernel<<<gC, blk, 0, stream>>>(Pa, Pb, Pc, 1.f + al[2], -al[2], n8);
    conv_big<3,2,1,2><<<gT2, cblk, 0, stream>>>(WTh1, Pc, NFo, r56h, NH, x,
        256, 128, 28, 28, 56, 56, 196, -1.f, 1.f, 0.f, 0, NF, NF, NF, 0, zpg);
    conv_big<3,2,1,0><<<gB, cblk, 0, stream>>>(Wh1, r56h, NFo, Py, Pc, NF,
        128, 256, 56, 56, 28, 28, 196, MU_F, 1.f, -SHRINK_F, 1, bn1s, bn1t, NF, 0, zpg);

    // ================= Stage B: dict_conv(y1, W2, stride 1) ================
    conv_big<3,1,1,0><<<gB, cblk, 0, stream>>>(Wh2, Py, NFo, Pa, NH, NF,
        256, 256, 28, 28, 28, 28, 196, MU_F, 0.f, -SHRINK_F, 1, NF, NF, NF, 0, zpg);

    conv_big<3,1,1,1><<<gB, cblk, 0, stream>>>(WTh2, Pa, NFo, r28h, Py, NF,
        256, 256, 28, 28, 28, 28, 196, -1.f, 1.f, 0.f, 0, NF, NF, NF, 0, zpg);
    conv_big<3,1,1,0><<<gB, cblk, 0, stream>>>(Wh2, r28h, NFo, Pb, Pa, NF,
        256, 256, 28, 28, 28, 28, 196, MU_F, 1.f, -SHRINK_F, 1, NF, NF, NF, 0, zpg);

    comb_kernel<<<gC, blk, 0, stream>>>(Pb, Pa, Pc, 1.f + al[1], -al[1], n8);
    conv_big<3,1,1,1><<<gB, cblk, 0, stream>>>(WTh2, Pc, NFo, r28h, Py, NF,
        256, 256, 28, 28, 28, 28, 196, -1.f, 1.f, 0.f, 0, NF, NF, NF, 0, zpg);
    conv_big<3,1,1,0><<<gB, cblk, 0, stream>>>(Wh2, r28h, NFo, Pa, Pc, NF,
        256, 256, 28, 28, 28, 28, 196, MU_F, 1.f, -SHRINK_F, 1, NF, NF, NF, 0, zpg);

    comb_kernel<<<gC, blk, 0, stream>>>(Pa, Pb, Pc, 1.f + al[2], -al[2], n8);
    conv_big<3,1,1,1><<<gB, cblk, 0, stream>>>(WTh2, Pc, NFo, r28h, Py, NF,
        256, 256, 28, 28, 28, 28, 196, -1.f, 1.f, 0.f, 0, NF, NF, NF, 0, zpg);
    conv_big<3,1,1,0><<<gB, cblk, 0, stream>>>(Wh2, r28h, outp, NHo, Pc, NF,
        256, 256, 28, 28, 28, 28, 196, MU_F, 1.f, -SHRINK_F, 1, bn2s, bn2t, scF, 1, zpg);
}

// Round 5
// 1316.756 us; speedup vs baseline: 1.0832x; 1.0832x over previous
//
#include <hip/hip_runtime.h>
#include <math.h>

#define MU_F 0.1f
#define SHRINK_F 0.01f   // LMBD * MU
#define BN_EPS_F 1e-5f

typedef _Float16 half_t;
typedef _Float16 half8 __attribute__((ext_vector_type(8)));
typedef float f32x4 __attribute__((ext_vector_type(4)));

// async global->LDS, 16B per lane. LDS dest is wave-uniform base + lane*16.
__device__ __forceinline__ void gll16(const half_t* g, half_t* l) {
    __builtin_amdgcn_global_load_lds(
        (const __attribute__((address_space(1))) void*)g,
        (__attribute__((address_space(3))) void*)l, 16, 0, 0);
}

// counted-vmcnt wait + raw barrier (verified 8-phase idiom; rule #18 hygiene).
#define VM_WAIT_BARRIER(N) do {                                   \
    asm volatile("s_waitcnt vmcnt(" #N ")" ::: "memory");         \
    __builtin_amdgcn_s_barrier();                                 \
    __builtin_amdgcn_sched_barrier(0);                            \
} while (0)

// ---------------------------------------------------------------------------
// MFMA implicit-GEMM conv (128co x 128px tile, 4 waves, K-chunk 32, 4-deep
// LDS ring with lookahead 3, counted vmcnt(8), tail 8->4->0).
// LDS swizzle: 16B slot s holds global slot s ^ ((row>>1)&3), applied on the
// global SOURCE (DMA dest is linear) and on the ds_read address (rule 21).
//   [round-4 fix: old (row&3) XOR'd against q8 which is constant within each
//    16-lane group -> systematic 4-way read conflict (1.8M cy/dispatch);
//    (row>>1)&3 spreads the 8 same-parity rows over 4 slots -> 2-way = free]
// MODE 0: fwd conv stride S pad PAD; MODE 1: convT s1 (pad 1).
// edge_defer: skip relu/BN for output px with oh==0||ow==0 (store raw
// pre-activation); a follow-up edge_fix kernel finishes them (Gram path).
// out2F: optionally also store alpha*acc (pre-delta/pre-act) fp32 NCHW.
// Frag layout (16x16x32): A row=l&15, k=(l>>4)*8+j ; B col=l&15 same k;
// C/D col=l&15, row=(l>>4)*4+reg  [m89-verified].
// ---------------------------------------------------------------------------
template<int KS, int S, int PAD, int MODE>
__global__ __launch_bounds__(256, 2)
void conv_big(const half_t* __restrict__ Ag, const half_t* __restrict__ Xh,
              float* __restrict__ outF, half_t* __restrict__ outH,
              const half_t* __restrict__ auxH, const float* __restrict__ auxF,
              int CA, int Cout, int Hin, int Win, int Hout, int Wout, int ptiles,
              float alpha, float beta, float delta, int relu1,
              const float* __restrict__ pscale, const float* __restrict__ pbias,
              const float* __restrict__ aux3, int relu2,
              const half_t* __restrict__ zpg, int edge_defer,
              float* __restrict__ out2F)
{
    __shared__ __align__(16) half_t sm[4 * 8192];   // 4 bufs x 256 rows x 32 halves = 64 KB

    const int tid = threadIdx.x;
    const int wv = tid >> 6, ln = tid & 63;
    const int co0 = blockIdx.y * 128;
    const int wco = (wv & 1) * 64, wpx = (wv >> 1) * 64;

    // bijective XCD swizzle (m204): works for any gridDim.x
    int bx;
    {
        const int nwg = gridDim.x;
        const int q = nwg >> 3, r8 = nwg & 7;
        const int xcd = blockIdx.x & 7, idx = blockIdx.x >> 3;
        bx = (xcd < r8 ? xcd * (q + 1) : r8 * (q + 1) + (xcd - r8) * q) + idx;
    }
    const int p0 = bx * 128;
    (void)ptiles;

    const int PHW1 = Hout * Wout;
    const int NPX  = PHW1 * 32;          // batch 32 folded into px space
    const int K9   = KS * KS * CA;

    const int r  = tid >> 2;             // 0..63: row within a 64-row DMA pass
    const int s4 = tid & 3;              // 16B slot
    const int sw = (s4 ^ ((r >> 1) & 3)) << 3;  // pre-swizzled source offset (halves)

    const size_t abase0 = (size_t)(co0 + r     ) * K9;
    const size_t abase1 = (size_t)(co0 + r + 64) * K9;

    int bph[2], bpw[2]; bool bval[2]; size_t bnb[2];
#pragma unroll
    for (int i = 0; i < 2; ++i) {
        int px = p0 + i * 64 + r;
        bval[i] = px < NPX;
        int pc = bval[i] ? px : 0;
        int n2 = pc / PHW1; int rem = pc - n2 * PHW1;
        int ph = rem / Wout;
        bph[i] = ph; bpw[i] = rem - ph * Wout;
        bnb[i] = (size_t)n2 * Hin * Win;
    }

    const int cpt = CA >> 5;             // 32-ch chunks per tap (4 or 8)
    const int lgc = (cpt == 8) ? 3 : 2;
    const int ntap = KS * KS;
    const int total = ntap << lgc;

    // issue one chunk's 4 DMA passes (2 x A 64-rows, 2 x B 64-rows) into dst
    auto issue = [&](int flat, half_t* dst) {
        const int ci = flat & (cpt - 1);
        const int ti = flat >> lgc;
        int kh, kw;
        if (KS == 3) {
            kh = (ti * 11) >> 5; kw = ti - 3 * kh;   // div-by-3, ti<9
        } else { kh = 0; kw = 0; }
        const int c0 = ci << 5;
        const size_t koff = (size_t)(kh * KS + kw) * CA + c0 + sw;
        gll16(Ag + abase0 + koff, dst +        tid * 8);
        gll16(Ag + abase1 + koff, dst + 2048 + tid * 8);
#pragma unroll
        for (int i = 0; i < 2; ++i) {
            int hh, ww2; bool ok = bval[i];
            if (MODE == 0) {
                hh = bph[i] * S - PAD + kh; ww2 = bpw[i] * S - PAD + kw;
                ok = ok && (unsigned)hh < (unsigned)Hin && (unsigned)ww2 < (unsigned)Win;
            } else {
                hh = bph[i] + PAD - kh; ww2 = bpw[i] + PAD - kw;
                ok = ok && (unsigned)hh < (unsigned)Hin && (unsigned)ww2 < (unsigned)Win;
            }
            const half_t* src = ok
                ? Xh + (bnb[i] + (size_t)(hh * Win + ww2)) * CA + c0 + sw
                : zpg;
            gll16(src, dst + 4096 + i * 2048 + tid * 8);
        }
    };

    f32x4 acc[4][4] = {};

    // prologue: chunks 0,1,2 in flight (12 loads); wait oldest 4, barrier
    issue(0, sm);
    issue(1, sm + 8192);
    issue(2, sm + 16384);
    VM_WAIT_BARRIER(8);

    const int fr = ln & 15, q8 = ln >> 4;
    const int sx = (q8 ^ ((fr >> 1) & 3)) << 3;
    const int rdA = (wco + fr) * 32 + sx;
    const int rdB = (128 + wpx + fr) * 32 + sx;

    for (int k = 0; k < total; ++k) {
        half_t* bufr = sm + (k & 3) * 8192;
        if (k + 3 < total)
            issue(k + 3, sm + ((k + 3) & 3) * 8192);
        half8 fa[4], fb[4];
#pragma unroll
        for (int m = 0; m < 4; ++m)
            fa[m] = *(const half8*)(bufr + rdA + m * 512);
#pragma unroll
        for (int t2 = 0; t2 < 4; ++t2)
            fb[t2] = *(const half8*)(bufr + rdB + t2 * 512);
#pragma unroll
        for (int m = 0; m < 4; ++m)
#pragma unroll
            for (int t2 = 0; t2 < 4; ++t2)
                acc[m][t2] = __builtin_amdgcn_mfma_f32_16x16x32_f16(fa[m], fb[t2], acc[m][t2], 0, 0, 0);
        if (k + 3 < total)      VM_WAIT_BARRIER(8);
        else if (k + 2 < total) VM_WAIT_BARRIER(4);
        else if (k + 1 < total) VM_WAIT_BARRIER(0);
    }

    // epilogue
    const int rg = ln >> 4;
#pragma unroll
    for (int t = 0; t < 4; ++t) {
        int px = p0 + wpx + t * 16 + fr;
        if (px >= NPX) continue;
        int n2 = px / PHW1; int rem = px - n2 * PHW1;
        int oh = rem / Wout, ow = rem - oh * Wout;
        size_t ghwc = ((size_t)(n2 * Hout + oh) * Wout + ow) * Cout;
        bool defer = edge_defer && (oh == 0 || ow == 0);
#pragma unroll
        for (int m = 0; m < 4; ++m) {
#pragma unroll
            for (int rr = 0; rr < 4; ++rr) {
                int co_l = co0 + wco + m * 16 + rg * 4 + rr;
                size_t fidx = ((size_t)(n2 * Cout + co_l) * Hout + oh) * Wout + ow;
                float av = alpha * acc[m][t][rr];
                if (out2F) out2F[fidx] = av;
                float v = av + delta;
                if (auxH) v += beta * (float)auxH[ghwc + co_l];
                if (auxF) v += beta * auxF[fidx];
                if (!defer) {
                    if (relu1) v = fmaxf(v, 0.f);
                    if (pscale) v = pscale[co_l] * v + pbias[co_l];
                    if (aux3) v += aux3[fidx];
                    if (relu2) v = fmaxf(v, 0.f);
                }
                if (outH) outH[ghwc + co_l] = (half_t)v;
                else      outF[fidx] = v;
            }
        }
    }
}

template<int KT>
__global__ __launch_bounds__(256)
void pack_w(const float* __restrict__ W, half_t* __restrict__ Wh,
            half_t* __restrict__ WTh, int Cin, int Cout, int do_norm)
{
    __shared__ float red[256];
    int co = blockIdx.x, tid = threadIdx.x;
    int CK = Cin * KT;
    const float* w = W + (size_t)co * CK;
    float inv = 1.f;
    if (do_norm) {
        float s = 0.f;
        for (int i = tid; i < CK; i += 256) { float v = w[i]; s += v * v; }
        red[tid] = s; __syncthreads();
        for (int o = 128; o > 0; o >>= 1) {
            if (tid < o) red[tid] += red[tid + o];
            __syncthreads();
        }
        inv = 1.f / (sqrtf(red[0]) + 1e-12f);
    }
    for (int i = tid; i < CK; i += 256) {
        int ci = i / KT, tap = i - ci * KT;
        half_t h = (half_t)(w[i] * inv);
        Wh[((size_t)co * KT + tap) * Cin + ci] = h;
        if (WTh) WTh[((size_t)ci * KT + tap) * Cout + co] = h;
    }
}

// ---------------------------------------------------------------------------
// Gram precompute: Gp[co][tap(kh,kw)][b] = sum_{ci,k2 valid} Wn[co][ci][k2] *
// Wn[b][ci][k2 + 2(1-tap)]   (stride-2 conv o convT composite, 3x3 kernel).
// Edge-correction tensors (terms the true padded composition drops at the
// j = -1 boundary, all with d=0 i.e. center tap, k2=0 on the pinned axis):
//   ChT[kw][b][co] (row 0), CwT[kh][b][co] (col 0), CcT[b][co] (corner).
// Wh layout: [co][tap][ci], ci<128, normalized.
// ---------------------------------------------------------------------------
__global__ __launch_bounds__(256)
void gram_kernel(const half_t* __restrict__ Wh, half_t* __restrict__ Gp,
                 half_t* __restrict__ ChT, half_t* __restrict__ CwT,
                 half_t* __restrict__ CcT)
{
    __shared__ float Wa[9 * 128];
    int co = blockIdx.x, b = threadIdx.x;
    for (int i = b; i < 9 * 128; i += 256) Wa[i] = (float)Wh[(size_t)co * 9 * 128 + i];
    __syncthreads();
    const half_t* Wb = Wh + (size_t)b * 9 * 128;
    auto dot = [&](int tA, int tB) {
        float s = 0.f;
        for (int c = 0; c < 128; ++c) s += Wa[tA * 128 + c] * (float)Wb[tB * 128 + c];
        return s;
    };
    auto lo = [](int t) { return (t == 2) ? 2 : 0; };
    auto hi = [](int t) { return (t == 1) ? 3 : ((t == 2) ? 3 : 1); };
    for (int th = 0; th < 3; ++th)
        for (int tw = 0; tw < 3; ++tw) {
            float s = 0.f;
            for (int kh = lo(th); kh < hi(th); ++kh)
                for (int kw = lo(tw); kw < hi(tw); ++kw)
                    s += dot(kh * 3 + kw, (kh + 2 - 2 * th) * 3 + (kw + 2 - 2 * tw));
            Gp[((size_t)co * 9 + th * 3 + tw) * 256 + b] = (half_t)s;
        }
    for (int tw = 0; tw < 3; ++tw) {
        float s = 0.f, s2 = 0.f;
        for (int k = lo(tw); k < hi(tw); ++k) {
            s  += dot(k, k + 2 - 2 * tw);                     // kh row 0 pinned
            s2 += dot(k * 3, (k + 2 - 2 * tw) * 3);           // kw col 0 pinned
        }
        ChT[((size_t)tw * 256 + b) * 256 + co] = (half_t)s;
        CwT[((size_t)tw * 256 + b) * 256 + co] = (half_t)s2;
    }
    CcT[(size_t)b * 256 + co] = (half_t)dot(0, 0);
}

// finish boundary px (oh==0 || ow==0) of a Gram-conv output:
// true = stored_preact + MU*(Ch-terms + Cw-terms - Cc corner), then relu(+BN).
__global__ __launch_bounds__(256)
void edge_fix(const half_t* __restrict__ a, half_t* out,
              const half_t* __restrict__ ChT, const half_t* __restrict__ CwT,
              const half_t* __restrict__ CcT,
              const float* __restrict__ ps, const float* __restrict__ pb)
{
    int i = blockIdx.x, n = blockIdx.y, co = threadIdx.x;
    int oh, ow;
    if (i < 28) { oh = 0; ow = i; } else { oh = i - 27; ow = 0; }
    float corr = 0.f;
    if (oh == 0) {
        for (int kw = 0; kw < 3; ++kw) {
            int pw = ow - 1 + kw;
            if ((unsigned)pw < 28u) {
                const half_t* ap = a + ((size_t)(n * 28 + 0) * 28 + pw) * 256;
                const half_t* cp = ChT + (size_t)kw * 256 * 256 + co;
                for (int b2 = 0; b2 < 256; ++b2)
                    corr += (float)cp[(size_t)b2 * 256] * (float)ap[b2];
            }
        }
    }
    if (ow == 0) {
        for (int kh = 0; kh < 3; ++kh) {
            int ph = oh - 1 + kh;
            if ((unsigned)ph < 28u) {
                const half_t* ap = a + ((size_t)(n * 28 + ph) * 28 + 0) * 256;
                const half_t* cp = CwT + (size_t)kh * 256 * 256 + co;
                for (int b2 = 0; b2 < 256; ++b2)
                    corr += (float)cp[(size_t)b2 * 256] * (float)ap[b2];
            }
        }
    }
    if (oh == 0 && ow == 0) {
        const half_t* ap = a + ((size_t)(n * 28) * 28) * 256;
        for (int b2 = 0; b2 < 256; ++b2)
            corr -= (float)CcT[(size_t)b2 * 256 + co] * (float)ap[b2];
    }
    size_t idx = ((size_t)(n * 28 + oh) * 28 + ow) * 256 + co;
    float v = (float)out[idx] + MU_F * corr;
    v = fmaxf(v, 0.f);
    if (ps) v = ps[co] * v + pb[co];
    out[idx] = (half_t)v;
}

__global__ __launch_bounds__(256)
void tx_kernel(const float* __restrict__ x, half_t* __restrict__ xTh)
{
    __shared__ __align__(16) half_t tl[56 * 136];
    int h = blockIdx.x, n = blockIdx.y, tid = threadIdx.x;
    for (int it = 0; it < 28; ++it) {
        int id = tid + it * 256;
        int c = id / 56, w0 = id - c * 56;
        tl[w0 * 136 + c] = (half_t)x[(((size_t)n * 128 + c) * 56 + h) * 56 + w0];
    }
    __syncthreads();
    if (tid < 224) {
        int w0 = tid >> 2, part = tid & 3;
        size_t base = (((size_t)n * 56 + h) * 56 + w0) * 128 + part * 32;
#pragma unroll
        for (int j = 0; j < 4; ++j)
            *(half8*)(xTh + base + j * 8) = *(const half8*)(tl + w0 * 136 + part * 32 + j * 8);
    }
}

__global__ __launch_bounds__(256)
void comb_kernel(const half_t* __restrict__ c, const half_t* __restrict__ p,
                 half_t* __restrict__ a, float w1, float w2, int n8)
{
    int i = blockIdx.x * 256 + threadIdx.x;
    if (i >= n8) return;
    half8 cv = ((const half8*)c)[i];
    half8 pv = ((const half8*)p)[i];
    half8 rres;
#pragma unroll
    for (int j = 0; j < 8; ++j) rres[j] = (half_t)(w1 * (float)cv[j] + w2 * (float)pv[j]);
    ((half8*)a)[i] = rres;
}

__global__ __launch_bounds__(256)
void bn_prep_kernel(const float* __restrict__ g, const float* __restrict__ b,
                    const float* __restrict__ m, const float* __restrict__ v,
                    float* __restrict__ s, float* __restrict__ t, int C)
{
    int i = blockIdx.x * 256 + threadIdx.x;
    if (i < C) {
        float sc = g[i] * rsqrtf(v[i] + BN_EPS_F);
        s[i] = sc; t[i] = b[i] - m[i] * sc;
    }
}

__global__ __launch_bounds__(128)
void zfill_kernel(half_t* __restrict__ p)
{
    p[threadIdx.x] = (half_t)0.f;   // 256 B zero page for OOB DMA redirect
}

extern "C" void kernel_launch(void* const* d_in, const int* in_sizes, int n_in,
                              void* d_out, int out_size, void* d_ws, size_t ws_size,
                              hipStream_t stream)
{
    (void)in_sizes; (void)n_in; (void)out_size;
    const float* x    = (const float*)d_in[0];
    const float* W1   = (const float*)d_in[1];
    const float* W2   = (const float*)d_in[2];
    const float* Wsc  = (const float*)d_in[3];
    const float* bn1g = (const float*)d_in[4];
    const float* bn1b = (const float*)d_in[5];
    const float* bn1m = (const float*)d_in[6];
    const float* bn1v = (const float*)d_in[7];
    const float* bn2g = (const float*)d_in[8];
    const float* bn2b = (const float*)d_in[9];
    const float* bn2m = (const float*)d_in[10];
    const float* bn2v = (const float*)d_in[11];
    const float* bscg = (const float*)d_in[12];
    const float* bscb = (const float*)d_in[13];
    const float* bscm = (const float*)d_in[14];
    const float* bscv = (const float*)d_in[15];

    const size_t NB = (size_t)32 * 256 * 28 * 28;
    const size_t NX = (size_t)32 * 128 * 56 * 56;

    char* base = (char*)d_ws;
    size_t off = 0;
    auto alloc = [&](size_t nbytes) -> void* {
        void* r = base + off;
        off = (off + nbytes + 255) & ~(size_t)255;
        return r;
    };
    half_t* Wh1  = (half_t*)alloc(294912 * 2);
    half_t* WTh1 = (half_t*)alloc(294912 * 2);   // unused now, kept for layout stability
    half_t* Wh2  = (half_t*)alloc(589824 * 2);
    half_t* WTh2 = (half_t*)alloc(589824 * 2);
    half_t* Wsch = (half_t*)alloc(32768 * 2);
    half_t* Gph  = (half_t*)alloc(589824 * 2);   // 256*9*256 Gram kernel
    half_t* ChT  = (half_t*)alloc(196608 * 2);
    half_t* CwT  = (half_t*)alloc(196608 * 2);
    half_t* CcT  = (half_t*)alloc(65536 * 2);
    float* bn1s = (float*)alloc(256 * 4);  float* bn1t = (float*)alloc(256 * 4);
    float* bn2s = (float*)alloc(256 * 4);  float* bn2t = (float*)alloc(256 * 4);
    float* bscs = (float*)alloc(256 * 4);  float* bsct = (float*)alloc(256 * 4);
    half_t* zpg  = (half_t*)alloc(256);
    half_t* xTh  = (half_t*)alloc(NX * 2);   // stage-A input; dead after c0+shortcut
    half_t* Pa   = (half_t*)alloc(NB * 2);
    half_t* Pb   = (half_t*)alloc(NB * 2);
    half_t* Pc   = (half_t*)alloc(NB * 2);
    half_t* Py   = (half_t*)alloc(NB * 2);
    half_t* r28h = (half_t*)alloc(NB * 2);
    float*  scF  = (float*)alloc(NB * 4);
    if (off > ws_size) return;
    (void)WTh1;

    // aliases: cxF (fp32 NCHW, NB*4 bytes) lives over Py+r28h (contiguous,
    // both dead during stage A); Pd (stage-B temp) lives over xTh (dead then).
    float*  cxF = (float*)Py;
    half_t* Pd  = (half_t*)xTh;

    float* outp = (float*)d_out;

    double t = 1.0; float al[3];
    for (int i = 0; i < 3; ++i) {
        double tn = (1.0 + sqrt(1.0 + 4.0 * t * t)) / 2.0;
        al[i] = (float)((t - 1.0) / tn); t = tn;
    }

    const dim3 blk(256);
    const dim3 cblk(256);
    const dim3 gB(196, 2, 1);      // 25088 px / 128 exact, 2 co-tiles
    const dim3 gE(55, 32, 1);      // edge_fix: 28 row-0 px + 27 col-0 px
    const int n8 = (int)(NB / 8);
    const dim3 gC((n8 + 255) / 256);
    const float* NF = nullptr;
    const half_t* NH = nullptr;
    float* NFo = nullptr;
    half_t* NHo = nullptr;

    pack_w<9><<<256, blk, 0, stream>>>(W1, Wh1, nullptr, 128, 256, 1);
    pack_w<9><<<256, blk, 0, stream>>>(W2, Wh2, WTh2, 256, 256, 1);
    pack_w<1><<<256, blk, 0, stream>>>(Wsc, Wsch, nullptr, 128, 256, 0);
    gram_kernel<<<256, blk, 0, stream>>>(Wh1, Gph, ChT, CwT, CcT);
    bn_prep_kernel<<<1, blk, 0, stream>>>(bn1g, bn1b, bn1m, bn1v, bn1s, bn1t, 256);
    bn_prep_kernel<<<1, blk, 0, stream>>>(bn2g, bn2b, bn2m, bn2v, bn2s, bn2t, 256);
    bn_prep_kernel<<<1, blk, 0, stream>>>(bscg, bscb, bscm, bscv, bscs, bsct, 256);
    zfill_kernel<<<1, dim3(128), 0, stream>>>(zpg);
    tx_kernel<<<dim3(56, 32), blk, 0, stream>>>(x, xTh);

    // ============ Stage A: dict_conv(x, W1, stride 2) — Gram form ==========
    // cx = MU*conv(x)  (cached fp32 NCHW);  c0 = shrink(cx)
    conv_big<3,2,1,0><<<gB, cblk, 0, stream>>>(Wh1, xTh, NFo, Pa, NH, NF,
        128, 256, 56, 56, 28, 28, 196, MU_F, 0.f, -SHRINK_F, 1, NF, NF, NF, 0, zpg, 0, cxF);
    conv_big<1,2,0,0><<<gB, cblk, 0, stream>>>(Wsch, xTh, scF, NHo, NH, NF,
        128, 256, 56, 56, 28, 28, 196, 1.f, 0.f, 0.f, 0, bscs, bsct, NF, 0, zpg, 0, NFo);

    // iter1 (a = c0 = Pa): c = shrink(a + cx - MU*G(a)) -> Pb
    conv_big<3,1,1,0><<<gB, cblk, 0, stream>>>(Gph, Pa, NFo, Pb, Pa, cxF,
        256, 256, 28, 28, 28, 28, 196, -MU_F, 1.f, -SHRINK_F, 1, NF, NF, NF, 0, zpg, 1, NFo);
    edge_fix<<<gE, cblk, 0, stream>>>(Pa, Pb, ChT, CwT, CcT, NF, NF);

    // iter2: a = (1+al1)Pb - al1*Pa -> Pc ; c -> Pa
    comb_kernel<<<gC, blk, 0, stream>>>(Pb, Pa, Pc, 1.f + al[1], -al[1], n8);
    conv_big<3,1,1,0><<<gB, cblk, 0, stream>>>(Gph, Pc, NFo, Pa, Pc, cxF,
        256, 256, 28, 28, 28, 28, 196, -MU_F, 1.f, -SHRINK_F, 1, NF, NF, NF, 0, zpg, 1, NFo);
    edge_fix<<<gE, cblk, 0, stream>>>(Pc, Pa, ChT, CwT, CcT, NF, NF);

    // iter3: a = (1+al2)Pa - al2*Pb -> Pc ; y1 = bn1(c) -> Pb
    comb_kernel<<<gC, blk, 0, stream>>>(Pa, Pb, Pc, 1.f + al[2], -al[2], n8);
    conv_big<3,1,1,0><<<gB, cblk, 0, stream>>>(Gph, Pc, NFo, Pb, Pc, cxF,
        256, 256, 28, 28, 28, 28, 196, -MU_F, 1.f, -SHRINK_F, 1, bn1s, bn1t, NF, 0, zpg, 1, NFo);
    edge_fix<<<gE, cblk, 0, stream>>>(Pc, Pb, ChT, CwT, CcT, bn1s, bn1t);

    // ================= Stage B: dict_conv(y1=Pb, W2, stride 1) =============
    conv_big<3,1,1,0><<<gB, cblk, 0, stream>>>(Wh2, Pb, NFo, Pa, NH, NF,
        256, 256, 28, 28, 28, 28, 196, MU_F, 0.f, -SHRINK_F, 1, NF, NF, NF, 0, zpg, 0, NFo);

    conv_big<3,1,1,1><<<gB, cblk, 0, stream>>>(WTh2, Pa, NFo, r28h, Pb, NF,
        256, 256, 28, 28, 28, 28, 196, -1.f, 1.f, 0.f, 0, NF, NF, NF, 0, zpg, 0, NFo);
    conv_big<3,1,1,0><<<gB, cblk, 0, stream>>>(Wh2, r28h, NFo, Pd, Pa, NF,
        256, 256, 28, 28, 28, 28, 196, MU_F, 1.f, -SHRINK_F, 1, NF, NF, NF, 0, zpg, 0, NFo);

    comb_kernel<<<gC, blk, 0, stream>>>(Pd, Pa, Pc, 1.f + al[1], -al[1], n8);
    conv_big<3,1,1,1><<<gB, cblk, 0, stream>>>(WTh2, Pc, NFo, r28h, Pb, NF,
        256, 256, 28, 28, 28, 28, 196, -1.f, 1.f, 0.f, 0, NF, NF, NF, 0, zpg, 0, NFo);
    conv_big<3,1,1,0><<<gB, cblk, 0, stream>>>(Wh2, r28h, NFo, Pa, Pc, NF,
        256, 256, 28, 28, 28, 28, 196, MU_F, 1.f, -SHRINK_F, 1, NF, NF, NF, 0, zpg, 0, NFo);

    comb_kernel<<<gC, blk, 0, stream>>>(Pa, Pd, Pc, 1.f + al[2], -al[2], n8);
    conv_big<3,1,1,1><<<gB, cblk, 0, stream>>>(WTh2, Pc, NFo, r28h, Pb, NF,
        256, 256, 28, 28, 28, 28, 196, -1.f, 1.f, 0.f, 0, NF, NF, NF, 0, zpg, 0, NFo);
    conv_big<3,1,1,0><<<gB, cblk, 0, stream>>>(Wh2, r28h, outp, NHo, Pc, NF,
        256, 256, 28, 28, 28, 28, 196, MU_F, 1.f, -SHRINK_F, 1, bn2s, bn2t, scF, 1, zpg, 0, NFo);
}